// Round 13
// baseline (195.266 us; speedup 1.0000x reference)
//
#include <hip/hip_runtime.h>

// Bahdanau additive attention, fp32, 2 kernels, fixed-max softmax + last-block combine.
// score[b,q,v] = S - 2*sum_u s_u/(1+Eq*Ek);  p = exp(score - Mhi), Mhi = S + sum_u max(-2s_u,0)
// => p = exp(SM - 2*a), SM = -2*sum_u max(-s_u, 0),  a = sum_u s_u * r_u
// query [TQ,B,D], value [TV,B,D], mask [TV,B] (int32), W1 [D,U], W2 [D,U], scale [U]

#define TQ 256
#define TV 1024
#define BB 4
#define DD 128
#define UU 128
#define QTILES 16   // TQ/16
#define VTILES 16   // TV/64
#define C2LOG2E 2.8853900817779268f   // 2*log2(e)

// 4-batched reciprocal: 17 VALU + 1 rcp per 4 score terms
#define QUAD(Av, Kv, sv, acc)                                      \
  { float d0 = __builtin_fmaf(Av.x, Kv.x, 1.f);                    \
    float d1 = __builtin_fmaf(Av.y, Kv.y, 1.f);                    \
    float d2 = __builtin_fmaf(Av.z, Kv.z, 1.f);                    \
    float d3 = __builtin_fmaf(Av.w, Kv.w, 1.f);                    \
    float m01 = d0 * d1, m23 = d2 * d3;                            \
    float R = __builtin_amdgcn_rcpf(m01 * m23);                    \
    float q01 = R * m23, q23 = R * m01;                            \
    acc = __builtin_fmaf(sv.x, q01 * d1, acc);                     \
    acc = __builtin_fmaf(sv.y, q01 * d0, acc);                     \
    acc = __builtin_fmaf(sv.z, q23 * d3, acc);                     \
    acc = __builtin_fmaf(sv.w, q23 * d2, acc); }

// ============ kernel 1: compact + SM (blocks 0..3) | LDS-free proj (rest) ==
__global__ __launch_bounds__(256) void prep_kernel(
    const float* __restrict__ query, const float* __restrict__ value,
    const float* __restrict__ W1, const float* __restrict__ W2,
    const int* __restrict__ mask, const float* __restrict__ scale,
    float* __restrict__ Eq, float* __restrict__ Ek,
    int* __restrict__ valid_idx, int* __restrict__ nvalid,
    float* __restrict__ SMp, int* __restrict__ cnt)
{
  __shared__ int   wsum[4];
  __shared__ float sred[2];
  const int t = threadIdx.x, lane = t & 63, wid = t >> 6;
  const int bid = blockIdx.x;

  if (bid < BB) {
    const int b = bid;
    if (bid == 0 && t < BB * QTILES) cnt[t] = 0;   // zero combine counters
    int m[4];
#pragma unroll
    for (int k = 0; k < 4; ++k) m[k] = mask[(4 * t + k) * BB + b] ? 1 : 0;
    int cntv = m[0] + m[1] + m[2] + m[3];
    int pre = cntv;
#pragma unroll
    for (int off = 1; off < 64; off <<= 1) {
      int y = __shfl_up(pre, off, 64);
      if (lane >= off) pre += y;
    }
    if (lane == 63) wsum[wid] = pre;
    // SM = -2 * sum_u max(-s_u, 0)
    float sv_ = (t < UU) ? scale[t] : 0.f;
    float ng = fmaxf(-sv_, 0.f);
#pragma unroll
    for (int off = 32; off > 0; off >>= 1) ng += __shfl_xor(ng, off, 64);
    if (t == 0)  sred[0] = ng;
    if (t == 64) sred[1] = ng;
    __syncthreads();
    int base = 0;
#pragma unroll
    for (int w = 0; w < 4; ++w) if (w < wid) base += wsum[w];
    int total = wsum[0] + wsum[1] + wsum[2] + wsum[3];
    int idx = base + pre - cntv;
#pragma unroll
    for (int k = 0; k < 4; ++k)
      if (m[k]) valid_idx[b * TV + (idx++)] = 4 * t + k;
    for (int i = t; i < TV; i += 256)
      if (i >= total) valid_idx[b * TV + i] = 0;  // pad with valid row 0
    if (t == 0) nvalid[b] = total;
    if (b == 0 && t == 0) SMp[0] = -2.f * (sred[0] + sred[1]);
  } else {
    const int R0 = (bid - BB) * 8;
    const bool isq = (R0 < TQ * BB);
    const float* X = isq ? query : value;
    const float* W = isq ? W1 : W2;
    float* E       = isq ? Eq : Ek;
    const int T    = isq ? TQ : TV;
    const int Rb   = isq ? R0 : (R0 - TQ * BB);
    const int uu_  = t & 127;
    const int half = t >> 7;
    const float* x0 = X + (size_t)(Rb + half * 4) * DD;  // wave-uniform rows
    float a0 = 0.f, a1 = 0.f, a2 = 0.f, a3 = 0.f;
#pragma unroll 8
    for (int d = 0; d < DD; ++d) {
      float wv = W[d * UU + uu_];               // coalesced L2 load
      a0 = __builtin_fmaf(x0[d], wv, a0);       // uniform x -> s_load
      a1 = __builtin_fmaf(x0[DD + d], wv, a1);
      a2 = __builtin_fmaf(x0[2 * DD + d], wv, a2);
      a3 = __builtin_fmaf(x0[3 * DD + d], wv, a3);
    }
    float av[4] = {a0, a1, a2, a3};
#pragma unroll
    for (int i = 0; i < 4; ++i) {
      int rf = Rb + half * 4 + i;
      int b2 = rf & (BB - 1), tt = rf >> 2;
      E[((size_t)b2 * T + tt) * UU + uu_] =
          __builtin_amdgcn_exp2f(av[i] * C2LOG2E);  // exp(2*proj)
    }
  }
}

// ============ kernel 2: partial scores+exp+PV per (b,q16,v64) + combine ====
__global__ __launch_bounds__(256, 3) void partial_kernel(
    const float* __restrict__ value,     // [TV,B,D]
    const float* __restrict__ Eq,        // [B,TQ,U]
    const float* __restrict__ Ek,        // [B,TV,U]
    const float* __restrict__ scale,     // [U]
    const float* __restrict__ SMp,       // [1]
    const int*   __restrict__ valid_idx, // [B,TV] (padded with 0)
    const int*   __restrict__ nvalid,    // [B]
    float* __restrict__ pctx,            // [B][QT][VT][16][128]
    float* __restrict__ psum,            // [B][QT][VT][16]
    int*   __restrict__ cnt,             // [B][QT]
    float* __restrict__ out)             // [TQ,B,D]
{
  const int vt = blockIdx.x, qt = blockIdx.y, b = blockIdx.z;
  const int q0 = qt * 16, v0 = vt * 64;
  const int t = threadIdx.x;
  const int nv = nvalid[b];
  const float SM = SMp[0];

  __shared__ float4 ek_lds[64 * 32];   // 32 KB, col ^ (row&7) swizzle; reused as part[16][128]
  __shared__ float4 eq_lds[16 * 32];   // 8 KB linear
  __shared__ float  pT[64][16];        // 4 KB: p transposed for PV broadcasts
  __shared__ int    oldv_sh;

  {  // stage Eq tile (16 rows x 128)
    const float4* gq = (const float4*)Eq + ((size_t)(b * TQ + q0)) * 32;
    eq_lds[t]       = gq[t];
    eq_lds[256 + t] = gq[256 + t];
  }
  {  // stage Ek tile (64 gathered compact rows), swizzled
    const float4* gk = (const float4*)Ek;
#pragma unroll
    for (int k = 0; k < 8; ++k) {
      int i = k * 256 + t;
      int r = i >> 5, c = i & 31;
      int vrow = valid_idx[b * TV + v0 + r];
      ek_lds[r * 32 + (c ^ (r & 7))] = gk[((size_t)(b * TV + vrow)) * 32 + c];
    }
  }
  __syncthreads();

  // ---- scores + exp: thread = (qp = t>>5 -> rows 2qp,2qp+1; vp = t&31 -> cols vp,vp+32)
  const int qp = t >> 5;
  const int vp = t & 31;
  const int sx = vp & 7;
  const float4* Ar0 = eq_lds + (2 * qp) * 32;
  const float4* Ar1 = Ar0 + 32;
  const float4* Kr0 = ek_lds + vp * 32;
  const float4* Kr1 = ek_lds + (vp + 32) * 32;
  const float4* S4  = (const float4*)scale;     // uniform -> scalar loads

  float a00 = 0.f, a01 = 0.f, a10 = 0.f, a11 = 0.f;
#pragma unroll 8
  for (int uu = 0; uu < 32; ++uu) {
    float4 A0 = Ar0[uu];
    float4 A1 = Ar1[uu];
    int cs = uu ^ sx;
    float4 K0 = Kr0[cs];
    float4 K1 = Kr1[cs];
    float4 sv = S4[uu];
    QUAD(A0, K0, sv, a00)
    QUAD(A0, K1, sv, a01)
    QUAD(A1, K0, sv, a10)
    QUAD(A1, K1, sv, a11)
  }
  // p = exp(SM - 2a); zero out compact-padding columns
  const bool vok0 = (v0 + vp) < nv;
  const bool vok1 = (v0 + vp + 32) < nv;
  float p00 = vok0 ? __expf(__builtin_fmaf(-2.f, a00, SM)) : 0.f;
  float p01 = vok1 ? __expf(__builtin_fmaf(-2.f, a01, SM)) : 0.f;
  float p10 = vok0 ? __expf(__builtin_fmaf(-2.f, a10, SM)) : 0.f;
  float p11 = vok1 ? __expf(__builtin_fmaf(-2.f, a11, SM)) : 0.f;

  // per-row partial sums over this v-tile (reduce across vp: 32 lanes)
  float r0 = p00 + p01, r1 = p10 + p11;
#pragma unroll
  for (int off = 1; off < 32; off <<= 1) {
    r0 += __shfl_xor(r0, off, 64);
    r1 += __shfl_xor(r1, off, 64);
  }
  const size_t gidx = (size_t)(b * QTILES + qt) * VTILES + vt;
  if (vp == 0) {
    psum[gidx * 16 + 2 * qp]     = r0;
    psum[gidx * 16 + 2 * qp + 1] = r1;
  }

  // transpose p into LDS for PV
  pT[vp][2 * qp]          = p00;
  pT[vp + 32][2 * qp]     = p01;
  pT[vp][2 * qp + 1]      = p10;
  pT[vp + 32][2 * qp + 1] = p11;
  __syncthreads();   // pT ready; ek_lds/eq_lds reads done (part buffer reuse ok)

  // ---- PV: thread = (vh = t>>7, d = t&127); acc over 16 q rows ----
  const int vh = t >> 7;
  const int d  = t & 127;
  float acc[16];
#pragma unroll
  for (int j = 0; j < 16; ++j) acc[j] = 0.f;

  const int ibase = vh * 32;
  for (int i = ibase; i < ibase + 32; ++i) {
    int vrow = valid_idx[b * TV + v0 + i];            // wave-uniform -> s_load
    float vv = value[((size_t)vrow * BB + b) * DD + d]; // coalesced over d
    float4 pa0 = *((const float4*)&pT[i][0]);          // wave-uniform -> broadcast
    float4 pa1 = *((const float4*)&pT[i][4]);
    float4 pa2 = *((const float4*)&pT[i][8]);
    float4 pa3 = *((const float4*)&pT[i][12]);
    acc[0]  = __builtin_fmaf(pa0.x, vv, acc[0]);
    acc[1]  = __builtin_fmaf(pa0.y, vv, acc[1]);
    acc[2]  = __builtin_fmaf(pa0.z, vv, acc[2]);
    acc[3]  = __builtin_fmaf(pa0.w, vv, acc[3]);
    acc[4]  = __builtin_fmaf(pa1.x, vv, acc[4]);
    acc[5]  = __builtin_fmaf(pa1.y, vv, acc[5]);
    acc[6]  = __builtin_fmaf(pa1.z, vv, acc[6]);
    acc[7]  = __builtin_fmaf(pa1.w, vv, acc[7]);
    acc[8]  = __builtin_fmaf(pa2.x, vv, acc[8]);
    acc[9]  = __builtin_fmaf(pa2.y, vv, acc[9]);
    acc[10] = __builtin_fmaf(pa2.z, vv, acc[10]);
    acc[11] = __builtin_fmaf(pa2.w, vv, acc[11]);
    acc[12] = __builtin_fmaf(pa3.x, vv, acc[12]);
    acc[13] = __builtin_fmaf(pa3.y, vv, acc[13]);
    acc[14] = __builtin_fmaf(pa3.z, vv, acc[14]);
    acc[15] = __builtin_fmaf(pa3.w, vv, acc[15]);
  }

  float* part = (float*)ek_lds;          // reuse as [16][128]
  if (vh == 1) {
#pragma unroll
    for (int j = 0; j < 16; ++j) part[j * 128 + d] = acc[j];
  }
  __syncthreads();
  if (vh == 0) {
    float* dst = pctx + gidx * (16 * 128);
#pragma unroll
    for (int j = 0; j < 16; ++j)
      dst[j * 128 + d] = acc[j] + part[j * 128 + d];
  }

  // ---- last-block combine for this (b, qt) group ----
  __syncthreads();
  __threadfence();   // release: pctx/psum writes visible device-wide
  if (t == 0)
    oldv_sh = __hip_atomic_fetch_add(&cnt[b * QTILES + qt], 1,
                                     __ATOMIC_ACQ_REL, __HIP_MEMORY_SCOPE_AGENT);
  __syncthreads();
  if (oldv_sh == VTILES - 1) {
    __threadfence();   // acquire: see all other blocks' pctx/psum writes
    const int dc = t & 127, qg = t >> 7;
    const size_t gbase = (size_t)(b * QTILES + qt) * VTILES;
#pragma unroll
    for (int j = 0; j < 8; ++j) {
      int q = qg * 8 + j;
      float tot = 0.f, s = 0.f;
      for (int v2 = 0; v2 < VTILES; ++v2) {          // fixed order: deterministic
        tot += pctx[(gbase + v2) * (16 * 128) + q * 128 + dc];
        s   += psum[(gbase + v2) * 16 + q];
      }
      out[((size_t)(q0 + q) * BB + b) * DD + dc] = tot * __builtin_amdgcn_rcpf(s);
    }
  }
}

extern "C" void kernel_launch(void* const* d_in, const int* in_sizes, int n_in,
                              void* d_out, int out_size, void* d_ws, size_t ws_size,
                              hipStream_t stream) {
  const float* query = (const float*)d_in[0];  // [TQ,B,D]
  const float* value = (const float*)d_in[1];  // [TV,B,D]
  const int*   mask  = (const int*)  d_in[2];  // [TV,B]
  const float* W1    = (const float*)d_in[3];  // [D,U]
  const float* W2    = (const float*)d_in[4];  // [D,U]
  const float* scale = (const float*)d_in[5];  // [U]
  float* out = (float*)d_out;

  float* Eq     = (float*)d_ws;                        // [B,TQ,U]   131072 f
  float* Ek     = Eq + (size_t)BB * TQ * UU;           // [B,TV,U]   524288 f
  float* pctx   = Ek + (size_t)BB * TV * UU;           // [B][16][16][16][128] 2097152 f
  float* psum   = pctx + (size_t)BB * QTILES * VTILES * 16 * 128;  // 16384 f
  float* SMp    = psum + (size_t)BB * QTILES * VTILES * 16;        // [1]
  int*   vidx   = (int*)(SMp + 1);                     // [B,TV]
  int*   nvalid = vidx + BB * TV;                      // [B]
  int*   cnt    = nvalid + BB;                         // [B*QTILES]

  prep_kernel<<<BB + (TQ + TV) * BB / 8, 256, 0, stream>>>(
      query, value, W1, W2, mask, scale, Eq, Ek, vidx, nvalid, SMp, cnt);
  partial_kernel<<<dim3(VTILES, QTILES, BB), 256, 0, stream>>>(
      value, Eq, Ek, scale, SMp, vidx, nvalid, pctx, psum, cnt, out);
}

// Round 14
// 44.888 us; speedup vs baseline: 4.3501x; 4.3501x over previous
//
#include <hip/hip_runtime.h>

// Bahdanau additive attention, fp32, mask-compacted, exp-factored scores.
// score[b,q,v] = S - 2*sum_u s_u / (1 + Eq[q,u]*Ek[v,u]),  E* = exp(2*proj)
// query [TQ,B,D], value [TV,B,D], mask [TV,B] (int32), W1 [D,U], W2 [D,U], scale [U]

#define TQ 256
#define TV 1024
#define BB 4
#define DD 128
#define UU 128
#define NEG_INF -1e9f
#define C2LOG2E 2.8853900817779268f   // 2*log2(e)

// ================= A: compact (blocks 0..3) + proj (blocks 4..643) =========
union SharedA {
  struct { float Wl[DD * UU]; float xs[8][DD]; } pj;   // 68 KB
  struct { int wsum[4]; float sred[2]; } cp;
};

__global__ __launch_bounds__(256) void prep_kernel(
    const float* __restrict__ query, const float* __restrict__ value,
    const float* __restrict__ W1, const float* __restrict__ W2,
    const int* __restrict__ mask, const float* __restrict__ scale,
    float* __restrict__ Eq, float* __restrict__ Ek,
    int* __restrict__ valid_idx, int* __restrict__ nvalid,
    float* __restrict__ Ssum)
{
  __shared__ SharedA u;
  const int t = threadIdx.x, lane = t & 63, wid = t >> 6;
  const int bid = blockIdx.x;

  if (bid < BB) {           // ---- compact (verified R6/R8) ----
    const int b = bid;
    int m[4];
#pragma unroll
    for (int k = 0; k < 4; ++k) m[k] = mask[(4 * t + k) * BB + b] ? 1 : 0;
    int cnt = m[0] + m[1] + m[2] + m[3];
    int pre = cnt;
#pragma unroll
    for (int off = 1; off < 64; off <<= 1) {
      int y = __shfl_up(pre, off, 64);
      if (lane >= off) pre += y;
    }
    if (lane == 63) u.cp.wsum[wid] = pre;
    float sv_ = (t < UU) ? scale[t] : 0.f;
#pragma unroll
    for (int off = 32; off > 0; off >>= 1) sv_ += __shfl_xor(sv_, off, 64);
    if (t == 0)  u.cp.sred[0] = sv_;
    if (t == 64) u.cp.sred[1] = sv_;
    __syncthreads();
    int base = 0;
#pragma unroll
    for (int w = 0; w < 4; ++w) if (w < wid) base += u.cp.wsum[w];
    int total = u.cp.wsum[0] + u.cp.wsum[1] + u.cp.wsum[2] + u.cp.wsum[3];
    int idx = base + pre - cnt;
#pragma unroll
    for (int k = 0; k < 4; ++k)
      if (m[k]) valid_idx[b * TV + (idx++)] = 4 * t + k;
    for (int i = t; i < TV; i += 256)
      if (i >= total) valid_idx[b * TV + i] = 0;  // pad with valid row 0
    if (t == 0) nvalid[b] = total;
    if (b == 0 && t == 0) Ssum[0] = u.cp.sred[0] + u.cp.sred[1];
  } else {                  // ---- proj (verified R6/R8) ----
    const int blk = bid - BB;
    const bool isq = blk < (TQ * BB / 8);
    const float* X = isq ? query : value;
    const float* W = isq ? W1 : W2;
    float* E       = isq ? Eq : Ek;
    const int T    = isq ? TQ : TV;
    const int R0   = (isq ? blk : blk - TQ * BB / 8) * 8;

    const float4* Wg = (const float4*)W;
    float4* Wl4 = (float4*)u.pj.Wl;
#pragma unroll
    for (int k = 0; k < 16; ++k)
      Wl4[k * 256 + t] = Wg[k * 256 + t];
    ((float4*)u.pj.xs)[t] = ((const float4*)(X + (size_t)R0 * DD))[t];
    __syncthreads();

    const int half = t >> 7;
    const int uu_ = t & 127;
    float a[4] = {0.f, 0.f, 0.f, 0.f};
#pragma unroll 4
    for (int d = 0; d < DD; ++d) {
      float wv = u.pj.Wl[d * UU + uu_];
#pragma unroll
      for (int i = 0; i < 4; ++i)
        a[i] += u.pj.xs[half * 4 + i][d] * wv;
    }
#pragma unroll
    for (int i = 0; i < 4; ++i) {
      int rf = R0 + half * 4 + i;
      int b2 = rf & (BB - 1), tt = rf >> 2;
      E[((size_t)b2 * T + tt) * UU + uu_] =
          __builtin_amdgcn_exp2f(a[i] * C2LOG2E);   // exp(2*proj)
    }
  }
}

// ================= B: scores, 32q x 64v tiles (thread = 4q x 2v) ===========
// 4-batched reciprocal: 17 VALU + 1 rcp per 4 score terms
#define QUAD(Av, Kv, sv, acc)                                      \
  { float d0 = __builtin_fmaf(Av.x, Kv.x, 1.f);                    \
    float d1 = __builtin_fmaf(Av.y, Kv.y, 1.f);                    \
    float d2 = __builtin_fmaf(Av.z, Kv.z, 1.f);                    \
    float d3 = __builtin_fmaf(Av.w, Kv.w, 1.f);                    \
    float m01 = d0 * d1, m23 = d2 * d3;                            \
    float R = __builtin_amdgcn_rcpf(m01 * m23);                    \
    float q01 = R * m23, q23 = R * m01;                            \
    acc = __builtin_fmaf(sv.x, q01 * d1, acc);                     \
    acc = __builtin_fmaf(sv.y, q01 * d0, acc);                     \
    acc = __builtin_fmaf(sv.z, q23 * d3, acc);                     \
    acc = __builtin_fmaf(sv.w, q23 * d2, acc); }

__global__ __launch_bounds__(256, 3) void scores_kernel(
    const float* __restrict__ Eq,        // [B,TQ,U]
    const float* __restrict__ Ek,        // [B,TV,U]
    const float* __restrict__ scale,     // [U]
    const float* __restrict__ Ssum,      // [1]
    const int*   __restrict__ valid_idx, // [B,TV]
    const int*   __restrict__ nvalid,    // [B]
    float* __restrict__ scores)          // [B,TQ,TV] compact-indexed
{
  const int b  = blockIdx.z;
  const int nv = nvalid[b];
  const int v0 = blockIdx.x * 64;
  if (v0 >= nv) return;
  const int q0 = blockIdx.y * 32;
  const int t  = threadIdx.x;

  __shared__ float4 eq_lds[32 * 32];   // 16 KB linear
  __shared__ float4 ek_lds[64 * 32];   // 32 KB, col ^ (row&7) swizzle
  __shared__ int    vidx[64];

  if (t < 64) vidx[t] = valid_idx[b * TV + v0 + t];
  {
    const float4* gq = (const float4*)Eq + ((size_t)(b * TQ + q0)) * 32;
#pragma unroll
    for (int k = 0; k < 4; ++k)
      eq_lds[k * 256 + t] = gq[k * 256 + t];
  }
  __syncthreads();
  {
    const float4* gk = (const float4*)Ek;
#pragma unroll
    for (int k = 0; k < 8; ++k) {
      int i = k * 256 + t;
      int r = i >> 5, c = i & 31;
      ek_lds[r * 32 + (c ^ (r & 7))] =
          gk[((size_t)(b * TV + vidx[r])) * 32 + c];
    }
  }
  __syncthreads();

  const int qp = t >> 5;             // 0..7 -> q rows 4qp..4qp+3
  const int vp = t & 31;             // v cols {vp, vp+32}
  const int sx = vp & 7;
  const float4* Ar0 = eq_lds + (4 * qp) * 32;
  const float4* Ar1 = Ar0 + 32;
  const float4* Ar2 = Ar0 + 64;
  const float4* Ar3 = Ar0 + 96;
  const float4* Kr0 = ek_lds + vp * 32;
  const float4* Kr1 = ek_lds + (vp + 32) * 32;
  const float4* S4  = (const float4*)scale;   // uniform -> scalar loads

  float a00 = 0.f, a01 = 0.f, a10 = 0.f, a11 = 0.f;
  float a20 = 0.f, a21 = 0.f, a30 = 0.f, a31 = 0.f;
#pragma unroll 4
  for (int uu = 0; uu < 32; ++uu) {
    float4 A0 = Ar0[uu];
    float4 A1 = Ar1[uu];
    float4 A2 = Ar2[uu];
    float4 A3 = Ar3[uu];
    int cs = uu ^ sx;
    float4 K0 = Kr0[cs];
    float4 K1 = Kr1[cs];
    float4 sv = S4[uu];
    QUAD(A0, K0, sv, a00)
    QUAD(A0, K1, sv, a01)
    QUAD(A1, K0, sv, a10)
    QUAD(A1, K1, sv, a11)
    QUAD(A2, K0, sv, a20)
    QUAD(A2, K1, sv, a21)
    QUAD(A3, K0, sv, a30)
    QUAD(A3, K1, sv, a31)
  }
  const float S = Ssum[0];
  float* row0 = scores + ((size_t)(b * TQ + q0 + 4 * qp)) * TV + v0;
  row0[vp]               = __builtin_fmaf(-2.f, a00, S);
  row0[vp + 32]          = __builtin_fmaf(-2.f, a01, S);
  row0[TV + vp]          = __builtin_fmaf(-2.f, a10, S);
  row0[TV + vp + 32]     = __builtin_fmaf(-2.f, a11, S);
  row0[2 * TV + vp]      = __builtin_fmaf(-2.f, a20, S);
  row0[2 * TV + vp + 32] = __builtin_fmaf(-2.f, a21, S);
  row0[3 * TV + vp]      = __builtin_fmaf(-2.f, a30, S);
  row0[3 * TV + vp + 32] = __builtin_fmaf(-2.f, a31, S);
}

// ================= C: softmax + context, 4 q rows / block, 512 threads =====
__global__ __launch_bounds__(512) void softmax_ctx_kernel(
    const float* __restrict__ value,     // [TV,B,D]
    const int*   __restrict__ valid_idx, // [B,TV]
    const int*   __restrict__ nvalid,    // [B]
    const float* __restrict__ scores,    // [B,TQ,TV] compact
    float* __restrict__ out)             // [TQ,B,D]
{
  const int bi = blockIdx.x;
  const int b  = bi >> 6;
  const int q0 = (bi & 63) * 4;
  const int nv = nvalid[b];
  const int t = threadIdx.x, lane = t & 63;

  __shared__ float p_lds[4][TV];       // 16 KB
  __shared__ int   vidx[TV];           // 4 KB
  __shared__ float redm[4][2];
  __shared__ float reds[4][2];
  __shared__ float part[3][4][DD];     // 6 KB

  if (t < 256) ((int4*)vidx)[t] = ((const int4*)(valid_idx + b * TV))[t];

  // ---- softmax: row j = t>>7, chunk c = t&127 handles f4 at c and c+128 ----
  const int j = t >> 7;
  const int c = t & 127;
  const int wslot = (t >> 6) & 1;

  const float* srow = scores + ((size_t)(b * TQ + q0 + j)) * TV;
  float4 x0 = ((const float4*)srow)[c];
  float4 x1 = ((const float4*)srow)[c + 128];
  const int e0 = 4 * c, e1 = 512 + 4 * c;
  x0.x = (e0 + 0 < nv) ? x0.x : NEG_INF;
  x0.y = (e0 + 1 < nv) ? x0.y : NEG_INF;
  x0.z = (e0 + 2 < nv) ? x0.z : NEG_INF;
  x0.w = (e0 + 3 < nv) ? x0.w : NEG_INF;
  x1.x = (e1 + 0 < nv) ? x1.x : NEG_INF;
  x1.y = (e1 + 1 < nv) ? x1.y : NEG_INF;
  x1.z = (e1 + 2 < nv) ? x1.z : NEG_INF;
  x1.w = (e1 + 3 < nv) ? x1.w : NEG_INF;

  float mm = fmaxf(fmaxf(fmaxf(x0.x, x0.y), fmaxf(x0.z, x0.w)),
                   fmaxf(fmaxf(x1.x, x1.y), fmaxf(x1.z, x1.w)));
#pragma unroll
  for (int off = 32; off > 0; off >>= 1)
    mm = fmaxf(mm, __shfl_xor(mm, off, 64));
  if (lane == 0) redm[j][wslot] = mm;
  __syncthreads();
  mm = fmaxf(redm[j][0], redm[j][1]);

  float4 p0, p1;
  p0.x = __expf(x0.x - mm); p0.y = __expf(x0.y - mm);
  p0.z = __expf(x0.z - mm); p0.w = __expf(x0.w - mm);
  p1.x = __expf(x1.x - mm); p1.y = __expf(x1.y - mm);
  p1.z = __expf(x1.z - mm); p1.w = __expf(x1.w - mm);
  ((float4*)&p_lds[j][0])[c]       = p0;   // masked entries -> p == 0
  ((float4*)&p_lds[j][0])[c + 128] = p1;

  float ss = ((p0.x + p0.y) + (p0.z + p0.w)) +
             ((p1.x + p1.y) + (p1.z + p1.w));
#pragma unroll
  for (int off = 32; off > 0; off >>= 1)
    ss += __shfl_xor(ss, off, 64);
  if (lane == 0) reds[j][wslot] = ss;
  __syncthreads();   // p_lds, vidx, reds all visible

  // ---- context: quarter = t>>7 strides chunks of 4 v; d = t&127 ----
  const int qtr = t >> 7;
  const int d = t & 127;
  const int nChunks = (nv + 3) >> 2;
  float a0 = 0.f, a1 = 0.f, a2 = 0.f, a3 = 0.f;
  const float* vbase = value + b * DD + d;
  for (int ch = qtr; ch < nChunks; ch += 4) {
    int4 id = ((const int4*)vidx)[ch];
    float4 q0v = ((const float4*)&p_lds[0][0])[ch];
    float4 q1v = ((const float4*)&p_lds[1][0])[ch];
    float4 q2v = ((const float4*)&p_lds[2][0])[ch];
    float4 q3v = ((const float4*)&p_lds[3][0])[ch];
    float v0_ = vbase[(size_t)id.x * (BB * DD)];   // coalesced over d
    float v1_ = vbase[(size_t)id.y * (BB * DD)];
    float v2_ = vbase[(size_t)id.z * (BB * DD)];
    float v3_ = vbase[(size_t)id.w * (BB * DD)];
    a0 = __builtin_fmaf(q0v.x, v0_, a0); a0 = __builtin_fmaf(q0v.y, v1_, a0);
    a0 = __builtin_fmaf(q0v.z, v2_, a0); a0 = __builtin_fmaf(q0v.w, v3_, a0);
    a1 = __builtin_fmaf(q1v.x, v0_, a1); a1 = __builtin_fmaf(q1v.y, v1_, a1);
    a1 = __builtin_fmaf(q1v.z, v2_, a1); a1 = __builtin_fmaf(q1v.w, v3_, a1);
    a2 = __builtin_fmaf(q2v.x, v0_, a2); a2 = __builtin_fmaf(q2v.y, v1_, a2);
    a2 = __builtin_fmaf(q2v.z, v2_, a2); a2 = __builtin_fmaf(q2v.w, v3_, a2);
    a3 = __builtin_fmaf(q3v.x, v0_, a3); a3 = __builtin_fmaf(q3v.y, v1_, a3);
    a3 = __builtin_fmaf(q3v.z, v2_, a3); a3 = __builtin_fmaf(q3v.w, v3_, a3);
  }
  if (qtr) {
    part[qtr - 1][0][d] = a0;
    part[qtr - 1][1][d] = a1;
    part[qtr - 1][2][d] = a2;
    part[qtr - 1][3][d] = a3;
  }
  __syncthreads();
  if (qtr == 0) {
    float tot[4] = {a0, a1, a2, a3};
#pragma unroll
    for (int jj = 0; jj < 4; ++jj) {
      float s = tot[jj] + part[0][jj][d] + part[1][jj][d] + part[2][jj][d];
      float iv = 1.f / (reds[jj][0] + reds[jj][1]);
      out[((size_t)(q0 + jj) * BB + b) * DD + d] = s * iv;
    }
  }
}

extern "C" void kernel_launch(void* const* d_in, const int* in_sizes, int n_in,
                              void* d_out, int out_size, void* d_ws, size_t ws_size,
                              hipStream_t stream) {
  const float* query = (const float*)d_in[0];  // [TQ,B,D]
  const float* value = (const float*)d_in[1];  // [TV,B,D]
  const int*   mask  = (const int*)  d_in[2];  // [TV,B]
  const float* W1    = (const float*)d_in[3];  // [D,U]
  const float* W2    = (const float*)d_in[4];  // [D,U]
  const float* scale = (const float*)d_in[5];  // [U]
  float* out = (float*)d_out;

  float* Eq      = (float*)d_ws;                    // [B,TQ,U]
  float* Ek      = Eq + (size_t)BB * TQ * UU;       // [B,TV,U]
  float* scores  = Ek + (size_t)BB * TV * UU;       // [B,TQ,TV]
  int*   vidx    = (int*)(scores + (size_t)BB * TQ * TV); // [B,TV]
  int*   nvalid  = vidx + BB * TV;                  // [B]
  float* Ssum    = (float*)(nvalid + BB);           // [1]

  prep_kernel<<<BB + (TQ + TV) * BB / 8, 256, 0, stream>>>(
      query, value, W1, W2, mask, scale, Eq, Ek, vidx, nvalid, Ssum);
  scores_kernel<<<dim3(TV / 64, TQ / 32, BB), 256, 0, stream>>>(
      Eq, Ek, scale, Ssum, vidx, nvalid, scores);
  softmax_ctx_kernel<<<BB * TQ / 4, 512, 0, stream>>>(
      value, vidx, nvalid, scores, out);
}